// Round 7
// baseline (760.352 us; speedup 1.0000x reference)
//
#include <hip/hip_runtime.h>
#include <hip/hip_bf16.h>
#include <stdint.h>
#include <stddef.h>

typedef __hip_bfloat16 bf16;
typedef __attribute__((ext_vector_type(8))) short short8;
typedef __attribute__((ext_vector_type(4))) float f32x4;

#define EPI_NONE 0
#define EPI_SILU 1
#define EPI_RES  2
#define OUT_BF16  0
#define OUT_F32   1
#define OUT_SPLIT 2
#define OUT_VT    3   // write C transposed into VT[b][d][token], token = row
#define OUT_STATS 4   // f32 C + fused per-column (over rows) max/sumexp partials

__device__ __forceinline__ void gll16(const bf16* g, char* l) {
    __builtin_amdgcn_global_load_lds(
        (const __attribute__((address_space(1))) void*)g,
        (__attribute__((address_space(3))) void*)l, 16, 0, 0);
}

struct Segs { const bf16* A[3]; const bf16* B[3]; };

// ---------------------------------------------------------------------------
// K-segmented m97-structure bf16 GEMM.
//   C = sum_s A_seg[s] @ B_seg[s]^T over NSEG segments, each kseg K-columns.
// bf16x3 split products expressed as segments (A:{Qh,Qh,Ql}, B:{Kh,Kl,Kh})
// => always split-0 staging: 2 LDS tiles (<=32KB), uniform 1-MFMA inner loop.
// BN in {128,64}. LDS XOR-swizzle => 0 bank conflicts (verified r3).
// XCD-aware bijective block swizzle (grids %8==0; verified r5).
// ---------------------------------------------------------------------------
template<int NSEG, int BN, int EPI, int OUT>
__global__ __launch_bounds__(256)
void gemm_seg(Segs sg, void* __restrict__ Cp, bf16* __restrict__ Clo,
              const float* __restrict__ Res,
              float* __restrict__ mp, float* __restrict__ zp,
              int kseg, int lda, int ldb, int ldc, int ldr,
              unsigned long long sA, unsigned long long sB, unsigned long long sC)
{
    constexpr int NWF = BN / 32;          // col fragments per wave = B stage issues

    const size_t zA = (size_t)blockIdx.z * sA;
    const size_t zB = (size_t)blockIdx.z * sB;
    const size_t zC = (size_t)blockIdx.z * sC;

    // XCD-aware bijective swizzle on the (x,y) plane (nwg % 8 == 0)
    unsigned nwg = gridDim.x * gridDim.y;
    unsigned lin = blockIdx.y * gridDim.x + blockIdx.x;
    unsigned cpx = nwg >> 3;
    unsigned swz = (lin & 7) * cpx + (lin >> 3);
    unsigned bxs = swz % gridDim.x, bys = swz / gridDim.x;

    const int t    = threadIdx.x;
    const int w    = t >> 6;
    const int lane = t & 63;
    const int wr   = w >> 1, wc = w & 1;
    const int lo   = lane & 15, hi = lane >> 4;
    const int brow = bys * 128;
    const int bcol = bxs * BN;

    __shared__ bf16 As[128 * 64];
    __shared__ bf16 Bs[BN * 64];
    __shared__ float smst[(OUT == OUT_STATS) ? 512 : 4];

    f32x4 acc[4][NWF];
#pragma unroll
    for (int m = 0; m < 4; ++m)
#pragma unroll
        for (int n = 0; n < NWF; ++n)
            acc[m][n] = (f32x4){0.f, 0.f, 0.f, 0.f};

    const int r0 = t >> 3;                             // row in 32-row stripe
    const int cswz = ((t & 7) ^ ((t >> 3) & 7)) * 8;   // inverse-swizzled src
    const int rA7  = lo & 7;                           // read-side row parity

#pragma unroll
    for (int s = 0; s < NSEG; ++s) {
        const bf16* Ag = sg.A[s] + zA;
        const bf16* Bg = sg.B[s] + zB;
        for (int k0 = 0; k0 < kseg; k0 += 64) {
#pragma unroll
            for (int i = 0; i < 4; ++i) {
                int r = i * 32 + r0;
                gll16(Ag + (size_t)(brow + r) * lda + (k0 + cswz),
                      (char*)As + i * 4096 + w * 1024);
            }
#pragma unroll
            for (int i = 0; i < NWF; ++i) {
                int r = i * 32 + r0;
                gll16(Bg + (size_t)(bcol + r) * ldb + (k0 + cswz),
                      (char*)Bs + i * 4096 + w * 1024);
            }
            __syncthreads();

#pragma unroll
            for (int kk = 0; kk < 64; kk += 32) {
                short8 aH[4], bH[NWF];
#pragma unroll
                for (int m = 0; m < 4; ++m) {
                    int idx = (wr * 64 + m * 16 + lo) * 64 +
                              ((((kk >> 3) + hi) ^ rA7) * 8);
                    aH[m] = *(const short8*)&As[idx];
                }
#pragma unroll
                for (int n = 0; n < NWF; ++n) {
                    int idx = (wc * (BN / 2) + n * 16 + lo) * 64 +
                              ((((kk >> 3) + hi) ^ rA7) * 8);
                    bH[n] = *(const short8*)&Bs[idx];
                }
#pragma unroll
                for (int m = 0; m < 4; ++m)
#pragma unroll
                    for (int n = 0; n < NWF; ++n)
                        acc[m][n] = __builtin_amdgcn_mfma_f32_16x16x32_bf16(
                            aH[m], bH[n], acc[m][n], 0, 0, 0);
            }
            __syncthreads();
        }
    }

    // ---- epilogue: C writes ----
#pragma unroll
    for (int m = 0; m < 4; ++m) {
#pragma unroll
        for (int n = 0; n < NWF; ++n) {
            if constexpr (OUT == OUT_VT) {
                int row0 = brow + wr * 64 + m * 16 + hi * 4;
                int col  = bcol + wc * (BN / 2) + n * 16 + lo;    // d index
                int bb = row0 >> 12, n0 = row0 & 4095;
                unsigned short u[4];
#pragma unroll
                for (int j = 0; j < 4; ++j) {
                    bf16 vb = __float2bfloat16(acc[m][n][j]);
                    u[j] = *(unsigned short*)&vb;
                }
                ushort4 pack = {u[0], u[1], u[2], u[3]};
                *(ushort4*)&((bf16*)Cp)[((size_t)(bb * 512 + col) << 12) + n0] = pack;
            } else {
#pragma unroll
                for (int j = 0; j < 4; ++j) {
                    int row = brow + wr * 64 + m * 16 + hi * 4 + j;
                    int col = bcol + wc * (BN / 2) + n * 16 + lo;
                    size_t idx = (size_t)row * ldc + col + zC;
                    float v = acc[m][n][j];
                    if (EPI == EPI_SILU) v = v / (1.f + __expf(-v));
                    if (EPI == EPI_RES)  v += Res[(size_t)row * ldr + col];
                    if (OUT == OUT_F32 || OUT == OUT_STATS) {
                        ((float*)Cp)[idx] = v;
                    } else if (OUT == OUT_BF16) {
                        ((bf16*)Cp)[idx] = __float2bfloat16(v);
                    } else if (OUT == OUT_SPLIT) {
                        bf16 vh = __float2bfloat16(v);
                        ((bf16*)Cp)[idx] = vh;
                        Clo[idx] = __float2bfloat16(v - __bfloat162float(vh));
                    }
                }
            }
        }
    }

    // ---- fused per-column (over the block's 128 rows) max/sumexp ----
    if constexpr (OUT == OUT_STATS) {
#pragma unroll
        for (int n = 0; n < NWF; ++n) {
            float ml = acc[0][n][0];
#pragma unroll
            for (int m = 0; m < 4; ++m)
#pragma unroll
                for (int j = 0; j < 4; ++j) ml = fmaxf(ml, acc[m][n][j]);
            float zl = 0.f;
#pragma unroll
            for (int m = 0; m < 4; ++m)
#pragma unroll
                for (int j = 0; j < 4; ++j) zl += __expf(acc[m][n][j] - ml);
            // reduce across hi lanes (lane bits 4,5): 16 -> 64 rows
#pragma unroll
            for (int d = 16; d <= 32; d <<= 1) {
                float mo = __shfl_xor(ml, d);
                float zo = __shfl_xor(zl, d);
                float nm = fmaxf(ml, mo);
                zl = zl * __expf(ml - nm) + zo * __expf(mo - nm);
                ml = nm;
            }
            if (hi == 0) {
                int c = wc * (BN / 2) + n * 16 + lo;
                smst[wr * 256 + c]       = ml;
                smst[wr * 256 + 128 + c] = zl;
            }
        }
        __syncthreads();
        if (t < 128) {                        // combine the two wr halves
            float m0 = smst[t],       z0 = smst[128 + t];
            float m1 = smst[256 + t], z1 = smst[384 + t];
            float nm = fmaxf(m0, m1);
            float zz = z0 * __expf(m0 - nm) + z1 * __expf(m1 - nm);
            size_t o = (size_t)(brow >> 7) * 4096 + bcol + t;
            mp[o] = nm;
            zp[o] = zz;
        }
    }
}

// ---- split x fp32 -> (hi, lo) bf16 pair, vectorized ----
__global__ void split_x_kernel(const float* __restrict__ x,
                               bf16* __restrict__ xh, bf16* __restrict__ xl)
{
    size_t i = ((size_t)blockIdx.x * 256 + threadIdx.x) * 4;
    float4 v = *(const float4*)(x + i);
    float vv[4] = {v.x, v.y, v.z, v.w};
    unsigned short rh[4], rl[4];
#pragma unroll
    for (int j = 0; j < 4; ++j) {
        bf16 h_ = __float2bfloat16(vv[j]);
        bf16 l_ = __float2bfloat16(vv[j] - __bfloat162float(h_));
        rh[j] = *(unsigned short*)&h_;
        rl[j] = *(unsigned short*)&l_;
    }
    ushort4 oh = {rh[0], rh[1], rh[2], rh[3]};
    ushort4 ol = {rl[0], rl[1], rl[2], rl[3]};
    *(ushort4*)(xh + i) = oh;
    *(ushort4*)(xl + i) = ol;
}

// ---- transpose + split all 10 weights in one dispatch (z = weight idx) ----
struct WPack { const float* W[10]; bf16* H[10]; bf16* L[10]; };

__global__ void transw_all_kernel(WPack p)
{
    const float* W  = p.W[blockIdx.z];
    bf16* WTh = p.H[blockIdx.z];
    bf16* WTl = p.L[blockIdx.z];
    __shared__ float tile[32][33];
    int bx = blockIdx.x * 32, by = blockIdx.y * 32;
    int tx = threadIdx.x, ty = threadIdx.y;      // (32, 8)
#pragma unroll
    for (int i = 0; i < 32; i += 8)
        tile[ty + i][tx] = W[(size_t)(by + ty + i) * 512 + bx + tx];
    __syncthreads();
#pragma unroll
    for (int i = 0; i < 32; i += 8) {
        float v = tile[tx][ty + i];
        bf16 h_ = __float2bfloat16(v);
        size_t idx = (size_t)(bx + ty + i) * 512 + by + tx;
        WTh[idx] = h_;
        if (WTl) WTl[idx] = __float2bfloat16(v - __bfloat162float(h_));
    }
}

// ---- combine 32 row-block partials -> mcol, rinv ----
__global__ void colstats_comb_kernel(const float* __restrict__ mp, const float* __restrict__ zp,
                                     float* __restrict__ mcol, float* __restrict__ rinv)
{
    int col = blockIdx.x * 256 + threadIdx.x;
    float m = -1e30f;
#pragma unroll
    for (int i = 0; i < 32; ++i) m = fmaxf(m, mp[i * 4096 + col]);
    float z = 0.f;
#pragma unroll
    for (int i = 0; i < 32; ++i) z += zp[i * 4096 + col] * __expf(mp[i * 4096 + col] - m);
    mcol[col] = m;
    rinv[col] = 1.f / z;
}

// ---- P[q,k] = bf16( exp(S[q,k] - mcol[k]) * rinv[k] ) ----
__global__ void exp_p_kernel(const float* __restrict__ S, const float* __restrict__ mcol,
                             const float* __restrict__ rinv, bf16* __restrict__ P)
{
    size_t i = ((size_t)blockIdx.x * 256 + threadIdx.x) * 4;
    int k = (int)(i & 4095);
    float4 s  = *(const float4*)(S + i);
    float4 mc = *(const float4*)(mcol + k);
    float4 rv = *(const float4*)(rinv + k);
    bf16 b0 = __float2bfloat16(__expf(s.x - mc.x) * rv.x);
    bf16 b1 = __float2bfloat16(__expf(s.y - mc.y) * rv.y);
    bf16 b2 = __float2bfloat16(__expf(s.z - mc.z) * rv.z);
    bf16 b3 = __float2bfloat16(__expf(s.w - mc.w) * rv.w);
    ushort4 o;
    o.x = *(unsigned short*)&b0; o.y = *(unsigned short*)&b1;
    o.z = *(unsigned short*)&b2; o.w = *(unsigned short*)&b3;
    *(ushort4*)(P + i) = o;
}

// ---------------------------------------------------------------------------
extern "C" void kernel_launch(void* const* d_in, const int* in_sizes, int n_in,
                              void* d_out, int out_size, void* d_ws, size_t ws_size,
                              hipStream_t stream)
{
    const int B = 4, N = 4096, D = 512;
    const size_t MALL = (size_t)B * N;          // 16384
    const size_t ND = MALL * D;                 // 8.4M elems
    const size_t NN = (size_t)N * N;            // 16.7M elems
    const size_t WW = (size_t)D * D;            // 262144
    const float* x = (const float*)d_in[0];
    const float* Wf[10];
    for (int i = 0; i < 10; ++i) Wf[i] = (const float*)d_in[1 + i];
    // Wf: 0 qW1, 1 qW2, 2 kW1, 3 kW2, 4 vW1, 5 vW2, 6 aWq, 7 aWk, 8 aWv, 9 Wout

    char* ws = (char*)d_ws;
    size_t off = 0;
    auto carve = [&](size_t bytes) -> char* {
        char* p = ws + off;
        off = (off + bytes + 255) & ~(size_t)255;
        return p;
    };

    // 5 consecutive 32-MiB planes (identical carve to round 5, proven fit):
    //   A: x split            -> P[0]
    //   B: (t1v) then hh      -> P[1]
    //   C: (hv)  then hl      -> P[2]
    //   D: t1h   then QKh     -> P[3]
    //   E: t1l   then QKl     -> O
    const size_t PLANE = NN * 2;                 // 33,554,432 B
    bf16* xh  = (bf16*)carve(PLANE);  bf16* xl  = xh + ND;     // A
    bf16* hh  = (bf16*)carve(PLANE);                           // B (t1v first)
    bf16* hl  = (bf16*)carve(PLANE);                           // C (hv first)
    bf16* t1h = (bf16*)carve(PLANE);                           // D -> QKh
    bf16* t1l = (bf16*)carve(PLANE);                           // E -> QKl
    float* S  = (float*)carve(NN * 4);                         // 64 MiB
    bf16* VT  = (bf16*)carve((size_t)B * D * N * 2);           // 16 MiB
    bf16* wc1H = (bf16*)carve(2 * WW * 2);  bf16* wc1L = (bf16*)carve(2 * WW * 2);
    bf16* wc2H = (bf16*)carve(2 * WW * 2);  bf16* wc2L = (bf16*)carve(2 * WW * 2);
    bf16* wcAH = (bf16*)carve(2 * WW * 2);  bf16* wcAL = (bf16*)carve(2 * WW * 2);
    bf16* wv1H = (bf16*)carve(WW * 2);
    bf16* wv2H = (bf16*)carve(WW * 2);
    bf16* wv3H = (bf16*)carve(WW * 2);
    bf16* woH  = (bf16*)carve(WW * 2);      bf16* woL  = (bf16*)carve(WW * 2);
    float* mp   = (float*)carve(32 * 4096 * 4);
    float* zp   = (float*)carve(32 * 4096 * 4);
    float* mcol = (float*)carve(4096 * 4);
    float* rinv = (float*)carve(4096 * 4);
    bf16* t1v = hh;          // v-branch scratch (before h is written)
    bf16* hv  = hl;
    bf16* QKh = t1h;         // [16384][1024]: cols 0-511 = Q, 512-1023 = K
    bf16* QKl = t1l;
    bf16* P_all = xh;        // planes A..D, stride NN
    bf16* O   = t1l;         // plane E after QK dead
    (void)in_sizes; (void)n_in; (void)out_size; (void)ws_size;

    // ---- input split + all weight transposes ----
    split_x_kernel<<<dim3((unsigned)(ND / 1024)), 256, 0, stream>>>(x, xh, xl);
    WPack wp;
    wp.W[0] = Wf[0]; wp.H[0] = wc1H;      wp.L[0] = wc1L;        // qW1
    wp.W[1] = Wf[2]; wp.H[1] = wc1H + WW; wp.L[1] = wc1L + WW;   // kW1
    wp.W[2] = Wf[1]; wp.H[2] = wc2H;      wp.L[2] = wc2L;        // qW2
    wp.W[3] = Wf[3]; wp.H[3] = wc2H + WW; wp.L[3] = wc2L + WW;   // kW2
    wp.W[4] = Wf[6]; wp.H[4] = wcAH;      wp.L[4] = wcAL;        // aWq
    wp.W[5] = Wf[7]; wp.H[5] = wcAH + WW; wp.L[5] = wcAL + WW;   // aWk
    wp.W[6] = Wf[4]; wp.H[6] = wv1H;      wp.L[6] = nullptr;     // vW1
    wp.W[7] = Wf[5]; wp.H[7] = wv2H;      wp.L[7] = nullptr;     // vW2
    wp.W[8] = Wf[8]; wp.H[8] = wv3H;      wp.L[8] = nullptr;     // aWv
    wp.W[9] = Wf[9]; wp.H[9] = woH;       wp.L[9] = woL;         // Wout
    transw_all_kernel<<<dim3(16, 16, 10), dim3(32, 8), 0, stream>>>(wp);

    auto seg1 = [](const bf16* a, const bf16* b) {
        Segs s; s.A[0] = a; s.A[1] = a; s.A[2] = a;
        s.B[0] = b; s.B[1] = b; s.B[2] = b; return s;
    };
    auto seg2 = [](const bf16* a0, const bf16* a1,
                   const bf16* b0, const bf16* b1) {
        Segs s; s.A[0] = a0; s.A[1] = a1; s.A[2] = a1;
        s.B[0] = b0; s.B[1] = b1; s.B[2] = b1; return s;
    };
    auto seg3 = [](const bf16* ah, const bf16* al,
                   const bf16* bh, const bf16* bl) {
        Segs s; s.A[0] = ah; s.A[1] = ah; s.A[2] = al;
        s.B[0] = bh; s.B[1] = bl; s.B[2] = bh; return s;
    };

    // ---- v branch (plain bf16, BN=64; scratch planes B,C; VT direct) ----
    gemm_seg<1, 64, EPI_SILU, OUT_BF16><<<dim3(8, 128), 256, 0, stream>>>(
        seg1(xh, wv1H), t1v, nullptr, nullptr, nullptr, nullptr,
        512, 512, 512, 512, 512, 0, 0, 0);
    gemm_seg<1, 64, EPI_RES, OUT_BF16><<<dim3(8, 128), 256, 0, stream>>>(
        seg1(t1v, wv2H), hv, nullptr, x, nullptr, nullptr,
        512, 512, 512, 512, 512, 0, 0, 0);
    gemm_seg<1, 64, EPI_NONE, OUT_VT><<<dim3(8, 128), 256, 0, stream>>>(
        seg1(hv, wv3H), VT, nullptr, nullptr, nullptr, nullptr,
        512, 512, 512, 512, 512, 0, 0, 0);

    // ---- q+k branches (bf16x3 as 3 K-segments, BN=128) ----
    gemm_seg<3, 128, EPI_SILU, OUT_SPLIT><<<dim3(8, 128), 256, 0, stream>>>(
        seg3(xh, xl, wc1H, wc1L), t1h, t1l, nullptr, nullptr, nullptr,
        512, 512, 512, 1024, 512, 0, 0, 0);
    gemm_seg<3, 128, EPI_RES, OUT_SPLIT><<<dim3(4, 128, 2), 256, 0, stream>>>(
        seg3(t1h, t1l, wc2H, wc2L), hh, hl, x, nullptr, nullptr,
        512, 1024, 512, 1024, 512, 512, WW, 512);
    gemm_seg<3, 128, EPI_NONE, OUT_SPLIT><<<dim3(4, 128, 2), 256, 0, stream>>>(
        seg3(hh, hl, wcAH, wcAL), QKh, QKl, nullptr, nullptr, nullptr,
        512, 1024, 512, 1024, 512, 512, WW, 512);

    // ---- per batch: S = QK^T (3 segments, fused col-stats); comb; P ----
    for (int b = 0; b < B; ++b) {
        size_t boff = (size_t)b * N * 1024;
        gemm_seg<3, 128, EPI_NONE, OUT_STATS><<<dim3(32, 32), 256, 0, stream>>>(
            seg3(QKh + boff, QKl + boff, QKh + boff + 512, QKl + boff + 512),
            S, nullptr, nullptr, mp, zp,
            512, 1024, 1024, 4096, 4096, 0, 0, 0);
        colstats_comb_kernel<<<16, 256, 0, stream>>>(mp, zp, mcol, rinv);
        exp_p_kernel<<<(unsigned)(NN / 1024), 256, 0, stream>>>(
            S, mcol, rinv, P_all + (size_t)b * NN);
    }

    // ---- z-batched PV: O[b] = P[b] @ VT[b]^T  (BN=64, kseg=4096) ----
    gemm_seg<1, 64, EPI_NONE, OUT_BF16><<<dim3(8, 32, 4), 256, 0, stream>>>(
        seg1(P_all, VT), O, nullptr, nullptr, nullptr, nullptr,
        4096, 4096, 4096, 512, 512,
        NN, (unsigned long long)D * N, (unsigned long long)N * D);

    // ---- final projection: d_out = O @ Wout (2 segments, BN=64) ----
    gemm_seg<2, 64, EPI_NONE, OUT_F32><<<dim3(8, 128), 256, 0, stream>>>(
        seg2(O, O, woH, woL), d_out, nullptr, nullptr, nullptr, nullptr,
        512, 512, 512, 512, 512, 0, 0, 0);
}